// Round 9
// baseline (181.601 us; speedup 1.0000x reference)
//
#include <hip/hip_runtime.h>
#include <hip/hip_fp16.h>

#define NMOL 128
#define LMAX 40
#define HDIM 256
#define NSYM 40
#define NCHG 5
#define NROWS (NMOL * LMAX)            // 5120 atoms

typedef __attribute__((ext_vector_type(8))) unsigned short ushx8;
typedef __attribute__((ext_vector_type(8))) _Float16 f16x8;
typedef __attribute__((ext_vector_type(2))) _Float16 f16x2;
typedef __attribute__((ext_vector_type(2))) __fp16 fp16x2r;   // cvt_pkrtz return type
typedef __attribute__((ext_vector_type(4))) float f32x4;

__device__ __forceinline__ float lrelu(float x) { return fmaxf(x, 0.01f * x); }

// ---------------------------------------------------------------------------
// GEMM: C[5120][1536] = x @ [W1s|W1c|W1b_u|W1b_v]^T + bias, inline f32->f16.
// Tile 64x64, 4 waves (2x2). A staged in LDS (XOR-swizzled, 32 KB only);
// B-fragments loaded DIRECT from global f32 (L2-resident W) + cvt in-register
// -> occupancy 3-4 blocks/CU instead of 2. cols<512 -> lrelu -> h; else uv.
// ---------------------------------------------------------------------------
__global__ __launch_bounds__(256) void gemm_kernel(
    const float* __restrict__ x,
    const float* __restrict__ W1s, const float* __restrict__ b1s,
    const float* __restrict__ W1c, const float* __restrict__ b1c,
    const float* __restrict__ W1b, const float* __restrict__ b1b,
    _Float16* __restrict__ hout, _Float16* __restrict__ uvp)
{
    __shared__ _Float16 As[64 * 256];   // 32 KB

    const int t  = threadIdx.x;
    const int m0 = blockIdx.x * 64;
    const int n0 = blockIdx.y * 64;     // region-aligned (regions at 256/512/1024)

    // block-uniform B source
    const float* Bsrc; int bstride; const float* bias_src;
    if (n0 < 256)       { Bsrc = W1s + (size_t)n0 * 256;            bstride = 256; bias_src = b1s + n0; }
    else if (n0 < 512)  { Bsrc = W1c + (size_t)(n0 - 256) * 256;    bstride = 256; bias_src = b1c + (n0 - 256); }
    else if (n0 < 1024) { Bsrc = W1b + (size_t)(n0 - 512) * 512;    bstride = 512; bias_src = b1b + (n0 - 512); }
    else                { Bsrc = W1b + (size_t)(n0 - 1024) * 512 + 256; bstride = 512; bias_src = nullptr; }

    // stage A only: 64 rows x 32 chunks(8 halfs) = 2048 chunks, 8 passes
    #pragma unroll
    for (int pass = 0; pass < 8; ++pass) {
        int gch = pass * 256 + t;
        int r = gch >> 5, c = gch & 31;
        int cs = c ^ (r & 7);
        const float* s = x + (size_t)(m0 + r) * 256 + c * 8;
        float4 a0 = *(const float4*)s, a1 = *(const float4*)(s + 4);
        union { f16x8 v; fp16x2r p[4]; } u;
        u.p[0] = __builtin_amdgcn_cvt_pkrtz(a0.x, a0.y);
        u.p[1] = __builtin_amdgcn_cvt_pkrtz(a0.z, a0.w);
        u.p[2] = __builtin_amdgcn_cvt_pkrtz(a1.x, a1.y);
        u.p[3] = __builtin_amdgcn_cvt_pkrtz(a1.z, a1.w);
        *(f16x8*)&As[r * 256 + cs * 8] = u.v;
    }
    __syncthreads();

    const int lane = t & 63, wave = t >> 6;
    const int wm = (wave >> 1) * 32, wn = (wave & 1) * 32;
    const int lr = lane & 15, lk = lane >> 4;       // lk in 0..3

    f32x4 acc[2][2] = {};
    #pragma unroll
    for (int ks = 0; ks < 8; ++ks) {
        f16x8 a[2], b[2];
        #pragma unroll
        for (int i = 0; i < 2; ++i) {
            int ra = wm + i * 16 + lr;
            int ca = (ks * 4 + lk) ^ (ra & 7);
            a[i] = *(const f16x8*)&As[ra * 256 + ca * 8];
            // B direct from global (L2-hit): row rb, k-cols (ks*4+lk)*8 .. +8
            int rb = wn + i * 16 + lr;
            const float* wr = Bsrc + (size_t)rb * bstride + (ks * 4 + lk) * 8;
            float4 w0 = *(const float4*)wr, w1 = *(const float4*)(wr + 4);
            union { f16x8 v; fp16x2r p[4]; } ub;
            ub.p[0] = __builtin_amdgcn_cvt_pkrtz(w0.x, w0.y);
            ub.p[1] = __builtin_amdgcn_cvt_pkrtz(w0.z, w0.w);
            ub.p[2] = __builtin_amdgcn_cvt_pkrtz(w1.x, w1.y);
            ub.p[3] = __builtin_amdgcn_cvt_pkrtz(w1.z, w1.w);
            b[i] = ub.v;
        }
        #pragma unroll
        for (int mi = 0; mi < 2; ++mi)
            #pragma unroll
            for (int ni = 0; ni < 2; ++ni)
                acc[mi][ni] = __builtin_amdgcn_mfma_f32_16x16x32_f16(a[mi], b[ni], acc[mi][ni], 0, 0, 0);
    }

    // epilogue: C row = m0+wm+mi*16+lk*4+rg, col = n0+wn+ni*16+lr
    #pragma unroll
    for (int mi = 0; mi < 2; ++mi) {
        #pragma unroll
        for (int ni = 0; ni < 2; ++ni) {
            int nl = wn + ni * 16 + lr;
            int ng = n0 + nl;
            float bs = bias_src ? bias_src[nl] : 0.0f;
            #pragma unroll
            for (int rg = 0; rg < 4; ++rg) {
                int row = m0 + wm + mi * 16 + lk * 4 + rg;
                float v = acc[mi][ni][rg] + bs;
                if (ng < 512) hout[(size_t)row * 512 + ng] = (_Float16)lrelu(v);
                else          uvp[(size_t)row * 1024 + (ng - 512)] = (_Float16)v;
            }
        }
    }
}

// ---------------------------------------------------------------------------
// consumer: block = (mol, half), 512 threads, 256 blocks total.
//   t <  390 : bond pairs (LDS-staged uv, XOR-swizzled, packed-f16 core)
//   t 390-429 (hf==0): diagonal bond rows
//   t >= 448 (wave 7, divergence-free): this block's 900 sym/chg dot products,
//             h read from global (L2-resident).
// ---------------------------------------------------------------------------
__global__ __launch_bounds__(512) void consumer_kernel(
    const _Float16* __restrict__ uv, const _Float16* __restrict__ h,
    const float* __restrict__ W2b, const float* __restrict__ b2b,
    const float* __restrict__ W2s, const float* __restrict__ b2s,
    const float* __restrict__ W2c, const float* __restrict__ b2c,
    float* __restrict__ out_sym, float* __restrict__ out_chg,
    float* __restrict__ out_bond)
{
    __shared__ unsigned short kv[40 * 1032];   // 82.5 KB

    const int t   = threadIdx.x;
    const int mol = blockIdx.x >> 1;
    const int hf  = blockIdx.x & 1;
    const unsigned short* uvm = (const unsigned short*)uv + (size_t)mol * 40 * 1024;

    #pragma unroll
    for (int pass = 0; pass < 10; ++pass) {
        int ch = pass * 512 + t;               // 0..5119 16B-chunks
        int r = ch >> 7, c = ch & 127;
        int cs = c ^ ((r >> 1) & 7);
        *(ushx8*)&kv[r * 1032 + cs * 8] = *(const ushx8*)(uvm + (size_t)r * 1024 + c * 8);
    }
    __syncthreads();

    if (t < 390) {
        int q = hf * 390 + t;
        int i = 0, rem = q;
        while (rem >= 39 - i) { rem -= 39 - i; ++i; }
        int j = i + 1 + rem;

        const int si = (i >> 1) & 7, sj = (j >> 1) & 7;
        const unsigned short* rowi = &kv[i * 1032];
        const unsigned short* rowj = &kv[j * 1032];
        const _Float16 c001 = (_Float16)0.01f;

        float a0 = 0.f, a1 = 0.f, a2 = 0.f, a3 = 0.f, a4 = 0.f;
        for (int p8 = 0; p8 < 64; ++p8) {
            union U8 { ushx8 u; f16x2 hh[4]; };
            U8 ui, vi, uj, vj;
            ui.u = *(const ushx8*)&rowi[(p8 ^ si) * 8];
            vi.u = *(const ushx8*)&rowi[(64 + (p8 ^ si)) * 8];
            uj.u = *(const ushx8*)&rowj[(p8 ^ sj) * 8];
            vj.u = *(const ushx8*)&rowj[(64 + (p8 ^ sj)) * 8];
            const float* wp = W2b + p8 * 8;    // uniform address -> scalar loads
            #pragma unroll
            for (int k = 0; k < 4; ++k) {
                f16x2 s1 = ui.hh[k] + vj.hh[k];
                f16x2 s2 = uj.hh[k] + vi.hh[k];
                f16x2 l1 = __builtin_elementwise_max(s1, s1 * c001);
                f16x2 l2 = __builtin_elementwise_max(s2, s2 * c001);
                f16x2 e  = l1 + l2;
                float ex = (float)e[0], ey = (float)e[1];
                a0 += ex * wp[2*k]        + ey * wp[2*k + 1];
                a1 += ex * wp[512 + 2*k]  + ey * wp[512 + 2*k + 1];
                a2 += ex * wp[1024 + 2*k] + ey * wp[1024 + 2*k + 1];
                a3 += ex * wp[1536 + 2*k] + ey * wp[1536 + 2*k + 1];
                a4 += ex * wp[2048 + 2*k] + ey * wp[2048 + 2*k + 1];
            }
        }
        const int base = mol * LMAX;
        float* o1 = out_bond + ((size_t)(base + i) * LMAX + j) * 5;
        float* o2 = out_bond + ((size_t)(base + j) * LMAX + i) * 5;
        float v0 = a0 + 2.f * b2b[0], v1 = a1 + 2.f * b2b[1], v2 = a2 + 2.f * b2b[2];
        float v3 = a3 + 2.f * b2b[3], v4 = a4 + 2.f * b2b[4];
        o1[0] = v0; o1[1] = v1; o1[2] = v2; o1[3] = v3; o1[4] = v4;
        o2[0] = v0; o2[1] = v1; o2[2] = v2; o2[3] = v3; o2[4] = v4;
    } else if (t >= 448) {
        // wave 7: heads layer-2. Tasks base..base+899 (r = task/45, m = task%45)
        const int base = hf * 900;
        for (int task = base + (t - 448); task < base + 900; task += 64) {
            int r = task / 45, m = task % 45;
            bool is_sym = (m < NSYM);
            int n = is_sym ? m : m - NSYM;
            const unsigned short* hrow = (const unsigned short*)h
                + ((size_t)(mol * LMAX + r)) * 512 + (is_sym ? 0 : 256);
            const float* wrow = is_sym ? (W2s + (size_t)n * 256) : (W2c + (size_t)n * 256);
            float acc = is_sym ? b2s[n] : b2c[n];
            for (int k8 = 0; k8 < 32; ++k8) {
                union { ushx8 u; f16x2 h2[4]; } hh;
                hh.u = *(const ushx8*)&hrow[k8 * 8];
                float4 w0 = *(const float4*)&wrow[k8 * 8];
                float4 w1 = *(const float4*)&wrow[k8 * 8 + 4];
                acc += (float)hh.h2[0][0]*w0.x + (float)hh.h2[0][1]*w0.y
                     + (float)hh.h2[1][0]*w0.z + (float)hh.h2[1][1]*w0.w
                     + (float)hh.h2[2][0]*w1.x + (float)hh.h2[2][1]*w1.y
                     + (float)hh.h2[3][0]*w1.z + (float)hh.h2[3][1]*w1.w;
            }
            int row = mol * LMAX + r;
            if (is_sym) out_sym[(size_t)row * NSYM + n] = acc;
            else        out_chg[(size_t)row * NCHG + n] = acc;
        }
    } else if (hf == 0 && t < 390 + LMAX) {
        int d = t - 390;
        float* o = out_bond + ((size_t)(mol * LMAX + d) * LMAX + d) * 5;
        o[0] = -1000.f; o[1] = -1000.f; o[2] = -1000.f; o[3] = -1000.f; o[4] = 1000.f;
    }
}

// ---------------------------------------------------------------------------
extern "C" void kernel_launch(void* const* d_in, const int* in_sizes, int n_in,
                              void* d_out, int out_size, void* d_ws, size_t ws_size,
                              hipStream_t stream)
{
    const float* x   = (const float*)d_in[0];
    const float* W1s = (const float*)d_in[1];
    const float* b1s = (const float*)d_in[2];
    const float* W2s = (const float*)d_in[3];
    const float* b2s = (const float*)d_in[4];
    const float* W1c = (const float*)d_in[5];
    const float* b1c = (const float*)d_in[6];
    const float* W2c = (const float*)d_in[7];
    const float* b2c = (const float*)d_in[8];
    const float* W1b = (const float*)d_in[9];
    const float* b1b = (const float*)d_in[10];
    const float* W2b = (const float*)d_in[11];
    const float* b2b = (const float*)d_in[12];

    float* out      = (float*)d_out;
    float* out_sym  = out;                                    // [5120, 40]
    float* out_chg  = out + (size_t)NROWS * NSYM;             // [5120, 5]
    float* out_bond = out + (size_t)NROWS * (NSYM + NCHG);    // [128*40*40, 5]

    char* ws = (char*)d_ws;
    const size_t H_B = (size_t)NROWS * 512 * 2;               // 5.24 MB
    _Float16* hbuf = (_Float16*)ws;                           // [5120][512]
    _Float16* uvp  = (_Float16*)(ws + H_B);                   // [5120][1024]

    dim3 gg(NROWS / 64, 1536 / 64);
    gemm_kernel<<<gg, 256, 0, stream>>>(x, W1s, b1s, W1c, b1c, W1b, b1b, hbuf, uvp);
    consumer_kernel<<<NMOL * 2, 512, 0, stream>>>(uvp, hbuf, W2b, b2b,
                                                  W2s, b2s, W2c, b2c,
                                                  out_sym, out_chg, out_bond);
}

// Round 11
// 164.491 us; speedup vs baseline: 1.1040x; 1.1040x over previous
//
#include <hip/hip_runtime.h>
#include <hip/hip_fp16.h>

#define NMOL 128
#define LMAX 40
#define HDIM 256
#define NSYM 40
#define NCHG 5
#define NROWS (NMOL * LMAX)            // 5120 atoms

typedef __attribute__((ext_vector_type(8))) unsigned short ushx8;
typedef __attribute__((ext_vector_type(8))) _Float16 f16x8;
typedef __attribute__((ext_vector_type(2))) _Float16 f16x2;
typedef __attribute__((ext_vector_type(2))) __fp16 fp16x2r;   // cvt_pkrtz return type
typedef __attribute__((ext_vector_type(4))) float f32x4;

__device__ __forceinline__ float lrelu(float x) { return fmaxf(x, 0.01f * x); }

// ---------------------------------------------------------------------------
// GEMM (round-8 proven): C[5120][1536] = x @ [W1s|W1c|W1b_u|W1b_v]^T + bias.
// Tile 64x64, 4 waves (2x2), 16x16x32 f16 MFMA. A and B staged in LDS with
// inline f32->f16 cvt_pkrtz, XOR-swizzled chunks. cols<512 -> lrelu -> h.
// ---------------------------------------------------------------------------
__global__ __launch_bounds__(256) void gemm_kernel(
    const float* __restrict__ x,
    const float* __restrict__ W1s, const float* __restrict__ b1s,
    const float* __restrict__ W1c, const float* __restrict__ b1c,
    const float* __restrict__ W1b, const float* __restrict__ b1b,
    _Float16* __restrict__ hout, _Float16* __restrict__ uvp)
{
    __shared__ _Float16 As[64 * 256];   // 32 KB
    __shared__ _Float16 Bs[64 * 256];   // 32 KB

    const int t  = threadIdx.x;
    const int m0 = blockIdx.x * 64;
    const int n0 = blockIdx.y * 64;     // region-aligned (regions at 256/512/1024)

    // block-uniform B source (no per-lane divergence)
    const float* Bsrc; int bstride; const float* bias_src;
    if (n0 < 256)       { Bsrc = W1s + (size_t)n0 * 256;            bstride = 256; bias_src = b1s + n0; }
    else if (n0 < 512)  { Bsrc = W1c + (size_t)(n0 - 256) * 256;    bstride = 256; bias_src = b1c + (n0 - 256); }
    else if (n0 < 1024) { Bsrc = W1b + (size_t)(n0 - 512) * 512;    bstride = 512; bias_src = b1b + (n0 - 512); }
    else                { Bsrc = W1b + (size_t)(n0 - 1024) * 512 + 256; bstride = 512; bias_src = nullptr; }

    #pragma unroll
    for (int pass = 0; pass < 8; ++pass) {
        int gch = pass * 256 + t;            // 0..2047 chunk id
        int r = gch >> 5, c = gch & 31;      // row 0..63, 8-elem chunk 0..31
        int cs = c ^ (r & 7);
        {
            const float* s = x + (size_t)(m0 + r) * 256 + c * 8;
            float4 a0 = *(const float4*)s, a1 = *(const float4*)(s + 4);
            union { f16x8 v; fp16x2r p[4]; } u;
            u.p[0] = __builtin_amdgcn_cvt_pkrtz(a0.x, a0.y);
            u.p[1] = __builtin_amdgcn_cvt_pkrtz(a0.z, a0.w);
            u.p[2] = __builtin_amdgcn_cvt_pkrtz(a1.x, a1.y);
            u.p[3] = __builtin_amdgcn_cvt_pkrtz(a1.z, a1.w);
            *(f16x8*)&As[r * 256 + cs * 8] = u.v;
        }
        {
            const float* s = Bsrc + (size_t)r * bstride + c * 8;
            float4 a0 = *(const float4*)s, a1 = *(const float4*)(s + 4);
            union { f16x8 v; fp16x2r p[4]; } u;
            u.p[0] = __builtin_amdgcn_cvt_pkrtz(a0.x, a0.y);
            u.p[1] = __builtin_amdgcn_cvt_pkrtz(a0.z, a0.w);
            u.p[2] = __builtin_amdgcn_cvt_pkrtz(a1.x, a1.y);
            u.p[3] = __builtin_amdgcn_cvt_pkrtz(a1.z, a1.w);
            *(f16x8*)&Bs[r * 256 + cs * 8] = u.v;
        }
    }
    __syncthreads();

    const int lane = t & 63, wave = t >> 6;
    const int wm = (wave >> 1) * 32, wn = (wave & 1) * 32;
    const int lr = lane & 15, lk = lane >> 4;       // lk in 0..3

    f32x4 acc[2][2] = {};
    #pragma unroll
    for (int ks = 0; ks < 8; ++ks) {
        f16x8 a[2], b[2];
        #pragma unroll
        for (int i = 0; i < 2; ++i) {
            int ra = wm + i * 16 + lr;
            int ca = (ks * 4 + lk) ^ (ra & 7);
            a[i] = *(const f16x8*)&As[ra * 256 + ca * 8];
            int rb = wn + i * 16 + lr;
            int cb = (ks * 4 + lk) ^ (rb & 7);
            b[i] = *(const f16x8*)&Bs[rb * 256 + cb * 8];
        }
        #pragma unroll
        for (int mi = 0; mi < 2; ++mi)
            #pragma unroll
            for (int ni = 0; ni < 2; ++ni)
                acc[mi][ni] = __builtin_amdgcn_mfma_f32_16x16x32_f16(a[mi], b[ni], acc[mi][ni], 0, 0, 0);
    }

    #pragma unroll
    for (int mi = 0; mi < 2; ++mi) {
        #pragma unroll
        for (int ni = 0; ni < 2; ++ni) {
            int nl = wn + ni * 16 + lr;
            int ng = n0 + nl;
            float bs = bias_src ? bias_src[nl] : 0.0f;
            #pragma unroll
            for (int rg = 0; rg < 4; ++rg) {
                int row = m0 + wm + mi * 16 + lk * 4 + rg;
                float v = acc[mi][ni][rg] + bs;
                if (ng < 512) hout[(size_t)row * 512 + ng] = (_Float16)lrelu(v);
                else          uvp[(size_t)row * 1024 + (ng - 512)] = (_Float16)v;
            }
        }
    }
}

// ---------------------------------------------------------------------------
// heads layer2 (round-8 proven): sym/chg from h f16 [5120][512]. 640 blocks,
// 8 KB LDS -> high occupancy, ~2 tasks/thread, latency fully hidden by TLP.
// ---------------------------------------------------------------------------
__global__ __launch_bounds__(256) void heads2_kernel(
    const _Float16* __restrict__ h,
    const float* __restrict__ W2s, const float* __restrict__ b2s,
    const float* __restrict__ W2c, const float* __restrict__ b2c,
    float* __restrict__ out_sym, float* __restrict__ out_chg)
{
    __shared__ unsigned short hsd[8 * 512];   // 8 KB
    const int t = threadIdx.x;
    const int r0 = blockIdx.x * 8;
    #pragma unroll
    for (int pass = 0; pass < 2; ++pass) {
        int ch = pass * 256 + t;              // 0..511
        *(ushx8*)&hsd[ch * 8] = *(const ushx8*)((const unsigned short*)h + (size_t)r0 * 512 + ch * 8);
    }
    __syncthreads();

    for (int idx = t; idx < 8 * (NSYM + NCHG); idx += 256) {
        int r = idx / (NSYM + NCHG), m = idx % (NSYM + NCHG);
        bool is_sym = (m < NSYM);
        int n = is_sym ? m : m - NSYM;
        const unsigned short* hrow = &hsd[r * 512 + (is_sym ? 0 : 256)];
        const float* wrow = is_sym ? (W2s + (size_t)n * 256) : (W2c + (size_t)n * 256);
        float acc = is_sym ? b2s[n] : b2c[n];
        for (int k8 = 0; k8 < 32; ++k8) {
            union { ushx8 u; f16x2 h2[4]; } hh;
            hh.u = *(const ushx8*)&hrow[k8 * 8];
            float4 w0 = *(const float4*)&wrow[k8 * 8];
            float4 w1 = *(const float4*)&wrow[k8 * 8 + 4];
            acc += (float)hh.h2[0][0]*w0.x + (float)hh.h2[0][1]*w0.y
                 + (float)hh.h2[1][0]*w0.z + (float)hh.h2[1][1]*w0.w
                 + (float)hh.h2[2][0]*w1.x + (float)hh.h2[2][1]*w1.y
                 + (float)hh.h2[3][0]*w1.z + (float)hh.h2[3][1]*w1.w;
        }
        int row = r0 + r;
        if (is_sym) out_sym[(size_t)row * NSYM + n] = acc;
        else        out_chg[(size_t)row * NCHG + n] = acc;
    }
}

// ---------------------------------------------------------------------------
// bonds: block = (mol, quarter), 256 threads, 512 blocks. LDS exactly 80 KB
// (stride 1024, no pad -> 2 blocks/CU; 512 blocks > 256 CUs so the doubled
// occupancy is realized). 195 pairs per block; quarter 0 writes diagonals.
// Packed-f16 core, W2b scalar f32 loads (wave-uniform address).
// ---------------------------------------------------------------------------
__global__ __launch_bounds__(256) void bonds_kernel3(
    const _Float16* __restrict__ uv, const float* __restrict__ W2b,
    const float* __restrict__ b2b, float* __restrict__ out_bond)
{
    __shared__ unsigned short kv[40 * 1024];   // 80 KB exactly

    const int t    = threadIdx.x;
    const int mol  = blockIdx.x >> 2;
    const int qblk = blockIdx.x & 3;
    const unsigned short* uvm = (const unsigned short*)uv + (size_t)mol * 40 * 1024;

    #pragma unroll
    for (int pass = 0; pass < 20; ++pass) {
        int ch = pass * 256 + t;               // 0..5119 16B-chunks
        int r = ch >> 7, c = ch & 127;
        int cs = c ^ ((r >> 1) & 7);
        *(ushx8*)&kv[r * 1024 + cs * 8] = *(const ushx8*)(uvm + (size_t)r * 1024 + c * 8);
    }
    __syncthreads();

    if (t < 195) {
        int q = qblk * 195 + t;
        int i = 0, rem = q;
        while (rem >= 39 - i) { rem -= 39 - i; ++i; }
        int j = i + 1 + rem;

        const int si = (i >> 1) & 7, sj = (j >> 1) & 7;
        const unsigned short* rowi = &kv[i * 1024];
        const unsigned short* rowj = &kv[j * 1024];
        const _Float16 c001 = (_Float16)0.01f;

        float a0 = 0.f, a1 = 0.f, a2 = 0.f, a3 = 0.f, a4 = 0.f;
        for (int p8 = 0; p8 < 64; ++p8) {
            union U8 { ushx8 u; f16x2 hh[4]; };
            U8 ui, vi, uj, vj;
            ui.u = *(const ushx8*)&rowi[(p8 ^ si) * 8];
            vi.u = *(const ushx8*)&rowi[(64 + (p8 ^ si)) * 8];
            uj.u = *(const ushx8*)&rowj[(p8 ^ sj) * 8];
            vj.u = *(const ushx8*)&rowj[(64 + (p8 ^ sj)) * 8];
            const float* wp = W2b + p8 * 8;    // uniform address -> scalar loads
            #pragma unroll
            for (int k = 0; k < 4; ++k) {
                f16x2 s1 = ui.hh[k] + vj.hh[k];   // u'_i + v_j
                f16x2 s2 = uj.hh[k] + vi.hh[k];   // u'_j + v_i
                f16x2 l1 = __builtin_elementwise_max(s1, s1 * c001);
                f16x2 l2 = __builtin_elementwise_max(s2, s2 * c001);
                f16x2 e  = l1 + l2;
                float ex = (float)e[0], ey = (float)e[1];
                a0 += ex * wp[2*k]        + ey * wp[2*k + 1];
                a1 += ex * wp[512 + 2*k]  + ey * wp[512 + 2*k + 1];
                a2 += ex * wp[1024 + 2*k] + ey * wp[1024 + 2*k + 1];
                a3 += ex * wp[1536 + 2*k] + ey * wp[1536 + 2*k + 1];
                a4 += ex * wp[2048 + 2*k] + ey * wp[2048 + 2*k + 1];
            }
        }
        const int base = mol * LMAX;
        float* o1 = out_bond + ((size_t)(base + i) * LMAX + j) * 5;
        float* o2 = out_bond + ((size_t)(base + j) * LMAX + i) * 5;
        float v0 = a0 + 2.f * b2b[0], v1 = a1 + 2.f * b2b[1], v2 = a2 + 2.f * b2b[2];
        float v3 = a3 + 2.f * b2b[3], v4 = a4 + 2.f * b2b[4];
        o1[0] = v0; o1[1] = v1; o1[2] = v2; o1[3] = v3; o1[4] = v4;
        o2[0] = v0; o2[1] = v1; o2[2] = v2; o2[3] = v3; o2[4] = v4;
    } else if (qblk == 0 && t < 195 + LMAX) {
        int d = t - 195;
        float* o = out_bond + ((size_t)(mol * LMAX + d) * LMAX + d) * 5;
        o[0] = -1000.f; o[1] = -1000.f; o[2] = -1000.f; o[3] = -1000.f; o[4] = 1000.f;
    }
}

// ---------------------------------------------------------------------------
extern "C" void kernel_launch(void* const* d_in, const int* in_sizes, int n_in,
                              void* d_out, int out_size, void* d_ws, size_t ws_size,
                              hipStream_t stream)
{
    const float* x   = (const float*)d_in[0];
    const float* W1s = (const float*)d_in[1];
    const float* b1s = (const float*)d_in[2];
    const float* W2s = (const float*)d_in[3];
    const float* b2s = (const float*)d_in[4];
    const float* W1c = (const float*)d_in[5];
    const float* b1c = (const float*)d_in[6];
    const float* W2c = (const float*)d_in[7];
    const float* b2c = (const float*)d_in[8];
    const float* W1b = (const float*)d_in[9];
    const float* b1b = (const float*)d_in[10];
    const float* W2b = (const float*)d_in[11];
    const float* b2b = (const float*)d_in[12];

    float* out      = (float*)d_out;
    float* out_sym  = out;                                    // [5120, 40]
    float* out_chg  = out + (size_t)NROWS * NSYM;             // [5120, 5]
    float* out_bond = out + (size_t)NROWS * (NSYM + NCHG);    // [128*40*40, 5]

    char* ws = (char*)d_ws;
    const size_t H_B = (size_t)NROWS * 512 * 2;               // 5.24 MB
    _Float16* hbuf = (_Float16*)ws;                           // [5120][512]
    _Float16* uvp  = (_Float16*)(ws + H_B);                   // [5120][1024]

    dim3 gg(NROWS / 64, 1536 / 64);
    gemm_kernel<<<gg, 256, 0, stream>>>(x, W1s, b1s, W1c, b1c, W1b, b1b, hbuf, uvp);
    bonds_kernel3<<<NMOL * 4, 256, 0, stream>>>(uvp, W2b, b2b, out_bond);
    heads2_kernel<<<NROWS / 8, 256, 0, stream>>>(hbuf, W2s, b2s, W2c, b2c, out_sym, out_chg);
}